// Round 10
// baseline (400.484 us; speedup 1.0000x reference)
//
#include <hip/hip_runtime.h>
#include <stdint.h>

typedef short short8 __attribute__((ext_vector_type(8)));
typedef float f32x4 __attribute__((ext_vector_type(4)));
typedef unsigned short u16;

#define T_TOK 8192
#define HID   2048
#define FFNW  1024
#define NE    8
#define NPAIR (2 * T_TOK)

#define VMCNT(n) asm volatile("s_waitcnt vmcnt(" #n ")" ::: "memory")
#define BAR() __builtin_amdgcn_s_barrier()

__device__ __forceinline__ unsigned short f2bf(float f) {
  unsigned int b = __float_as_uint(f);
  b += 0x7fffu + ((b >> 16) & 1u);   // RNE
  return (unsigned short)(b >> 16);
}
__device__ __forceinline__ float bf2f(unsigned short u) {
  return __uint_as_float(((unsigned)u) << 16);
}

#define GLOAD16(gptr, lptr)                                                          \
  __builtin_amdgcn_global_load_lds(                                                  \
      (const __attribute__((address_space(1))) unsigned int*)(gptr),                 \
      (__attribute__((address_space(3))) unsigned int*)(lptr), 16, 0, 0)

// ---------------- cast f32 -> bf16 (8 elems/thread) ----------------
__global__ __launch_bounds__(256) void k_cast(const float* __restrict__ in,
                                              unsigned short* __restrict__ out,
                                              long n8) {
  long i = (long)blockIdx.x * blockDim.x + threadIdx.x;
  long stride = (long)gridDim.x * blockDim.x;
  for (; i < n8; i += stride) {
    const float4* p = (const float4*)(in + i * 8);
    float4 a = p[0], b = p[1];
    uint4 o;
    o.x = (unsigned)f2bf(a.x) | ((unsigned)f2bf(a.y) << 16);
    o.y = (unsigned)f2bf(a.z) | ((unsigned)f2bf(a.w) << 16);
    o.z = (unsigned)f2bf(b.x) | ((unsigned)f2bf(b.y) << 16);
    o.w = (unsigned)f2bf(b.z) | ((unsigned)f2bf(b.w) << 16);
    ((uint4*)out)[i] = o;
  }
}

// ------------- router: wave per token, also emits xb = bf16(x). NO atomics. -------------
__global__ __launch_bounds__(256) void k_router(const float* __restrict__ x,
                                                const float* __restrict__ gw,
                                                unsigned short* __restrict__ xb,
                                                float* __restrict__ logits,
                                                int* __restrict__ sel,
                                                float* __restrict__ cw) {
  int wid = threadIdx.x >> 6, lane = threadIdx.x & 63;
  int t = blockIdx.x * 4 + wid;
  const float4* xr = (const float4*)(x + (size_t)t * HID);
  float acc[NE];
#pragma unroll
  for (int e = 0; e < NE; e++) acc[e] = 0.f;
  for (int i = lane; i < HID / 4; i += 64) {
    float4 xv = xr[i];
    ushort4 o;
    o.x = f2bf(xv.x); o.y = f2bf(xv.y); o.z = f2bf(xv.z); o.w = f2bf(xv.w);
    *(ushort4*)(xb + (size_t)t * HID + i * 4) = o;
#pragma unroll
    for (int e = 0; e < NE; e++) {
      float4 gv = ((const float4*)(gw + (size_t)e * HID))[i];
      acc[e] += xv.x * gv.x + xv.y * gv.y + xv.z * gv.z + xv.w * gv.w;
    }
  }
#pragma unroll
  for (int e = 0; e < NE; e++)
    for (int off = 32; off; off >>= 1) acc[e] += __shfl_down(acc[e], off);
  if (lane == 0) {
    float mx = acc[0];
#pragma unroll
    for (int e = 1; e < NE; e++) mx = fmaxf(mx, acc[e]);
    float p[NE];
#pragma unroll
    for (int e = 0; e < NE; e++) p[e] = expf(acc[e] - mx);
    int i1 = 0; float b1 = p[0];
#pragma unroll
    for (int e = 1; e < NE; e++) if (p[e] > b1) { b1 = p[e]; i1 = e; }
    int i2 = -1; float b2 = -1.f;
#pragma unroll
    for (int e = 0; e < NE; e++) if (e != i1 && p[e] > b2) { b2 = p[e]; i2 = e; }
    float denom = b1 + b2;
#pragma unroll
    for (int e = 0; e < NE; e++) logits[(size_t)t * NE + e] = acc[e];
    sel[2 * t] = i1; sel[2 * t + 1] = i2;
    cw[2 * t] = b1 / denom; cw[2 * t + 1] = b2 / denom;
  }
}

// ------- counting sort, phase 1: per-block ballot multi-split (no atomics) -------
__global__ __launch_bounds__(256) void k_count(const int* __restrict__ sel,
                                               u16* __restrict__ lrank,
                                               int* __restrict__ blkcnt) {
  int blk = blockIdx.x, tid = threadIdx.x;
  int t = blk * 256 + tid;
  int e0 = sel[2 * t], e1 = sel[2 * t + 1];
  int wave = tid >> 6, lane = tid & 63;
  unsigned long long below = (1ull << lane) - 1ull;

  int r0 = 0, r1 = 0, c0[NE], c1[NE];
#pragma unroll
  for (int e = 0; e < NE; e++) {
    unsigned long long m = __ballot(e0 == e);
    if (e == e0) r0 = __popcll(m & below);
    c0[e] = __popcll(m);
  }
#pragma unroll
  for (int e = 0; e < NE; e++) {
    unsigned long long m = __ballot(e1 == e);
    if (e == e1) r1 = __popcll(m & below);
    c1[e] = __popcll(m);
  }

  __shared__ int wcnt[4][NE];
  if (lane < NE) wcnt[wave][lane] = c0[lane] + c1[lane];
  __syncthreads();

  int pre0 = 0, pre1 = 0;
  for (int w = 0; w < wave; w++) { pre0 += wcnt[w][e0]; pre1 += wcnt[w][e1]; }
  lrank[2 * t]     = (u16)(pre0 + r0);
  lrank[2 * t + 1] = (u16)(pre1 + c0[e1] + r1);

  if (tid < NE) {
    int s = 0;
    for (int w = 0; w < 4; w++) s += wcnt[w][tid];
    blkcnt[blk * NE + tid] = s;
  }
}

// ------- counting sort, phase 2: tiny scan (redundant per block) + place -------
// Also emits mpre[9]: prefix of ceil(count_e/256) for the GEMM work-item list.
__global__ __launch_bounds__(256) void k_scanplace(const int* __restrict__ sel,
                                                   const u16* __restrict__ lrank,
                                                   const int* __restrict__ blkcnt,
                                                   int* __restrict__ tokc,
                                                   int* __restrict__ inv,
                                                   int* __restrict__ counts,
                                                   int* __restrict__ base_,
                                                   int* __restrict__ mpre) {
  int blk = blockIdx.x, tid = threadIdx.x;
  __shared__ int s_pre[NE], s_tot[NE], s_base[NE + 1];
  if (tid < NE) {
    int run = 0, tot = 0;
    for (int b = 0; b < 32; b++) {
      int c = blkcnt[b * NE + tid];
      if (b < blk) run += c;
      tot += c;
    }
    s_pre[tid] = run;
    s_tot[tid] = tot;
  }
  __syncthreads();
  if (tid == 0) {
    int a = 0;
    for (int e = 0; e < NE; e++) { s_base[e] = a; a += s_tot[e]; }
    s_base[NE] = a;
  }
  __syncthreads();

  int t = blk * 256 + tid;
#pragma unroll
  for (int k = 0; k < 2; k++) {
    int e = sel[2 * t + k];
    int pos = s_base[e] + s_pre[e] + (int)lrank[2 * t + k];
    tokc[pos] = t;
    inv[2 * t + k] = pos;
  }
  if (blk == 0) {
    if (tid < NE) {
      counts[tid] = s_tot[tid];
      base_[tid] = s_base[tid];
    }
    if (tid == 0) {
      int a = 0;
      for (int e = 0; e < NE; e++) { mpre[e] = a; a += (s_tot[e] + 255) >> 8; }
      mpre[NE] = a;
    }
  }
}

// XCD-aware remap (nwg % 8 == 0): XCD gets a contiguous chunk -> expert locality.
__device__ __forceinline__ int xcd_remap(int L, int nwg) {
  return (L & 7) * (nwg >> 3) + (L >> 3);
}

// ====== 8-phase MFMA GEMM over a flattened work-item list ======
// Items = Σ_e ceil(cnt_e/256) × 8 n-blocks; block bid handles items bid, bid+512,...
// Extra items (>512) land on the LOWEST bids, which dispatch first -> makespan 2·t_b.
// Per item: identical proven r8 schedule (BK=64, 2 dbufs, 4 quadrant phases,
// counted VMCNT(4) at end-of-tile, VMCNT(0) at T==NT-2, prologue VMCNT(4)+BAR).
// XOR chunk-swizzle both sides: 0 bank conflicts (measured r2-r9).
template<bool FUSED, int KD, int ND>
__global__ __launch_bounds__(512, 2) void k_gemm(const u16* __restrict__ A,
                                                 const u16* __restrict__ W,
                                                 u16* __restrict__ Y,
                                                 const int* __restrict__ counts,
                                                 const int* __restrict__ base_,
                                                 const int* __restrict__ tokc,
                                                 const int* __restrict__ mpre) {
  int bid = xcd_remap(blockIdx.x, 512);
  constexpr int NCOL = FUSED ? 128 : 256;

  int mp[NE + 1];
#pragma unroll
  for (int k = 0; k <= NE; k++) mp[k] = mpre[k];
  int NI = mp[NE] * 8;

  int tid = threadIdx.x;
  int wave = tid >> 6, lane = tid & 63;
  int qrow = tid >> 3;    // 0..63
  int cph = tid & 7;      // physical 16B chunk within 128B row

  // item-invariant LDS destinations + B-row decode
  unsigned adst[2][2], bdst[2][2];
  int rBl[2][2];
#pragma unroll
  for (int u = 0; u < 2; u++) {
#pragma unroll
    for (int j = 0; j < 2; j++) {
      int rA = qrow + u * 64 + j * 128;
      adst[u][j] = (unsigned)(rA * 64 + cph * 8);
      int rB;
      if (FUSED) rB = qrow + u * 128 + j * 64;
      else       rB = (qrow >> 5) * 64 + (qrow & 31) + u * 32 + j * 128;
      rBl[u][j] = rB;
      bdst[u][j] = (unsigned)(16384 + rB * 64 + cph * 8);
    }
  }

  int wm = wave >> 2, wn = wave & 3;   // 2M x 4N
  int arow = wm * 128;
  int frow = lane & 15, fk = lane >> 4;
  int sw[2];
  sw[0] = ((fk) ^ (frow & 7)) << 4;
  sw[1] = ((fk + 4) ^ (frow & 7)) << 4;

  constexpr int NT = KD / 64;

  __shared__ u16 lds[2 * 32768];   // 2 dbufs x 64KB: A[256][64] @0, B[256][64] @16384

  for (int item = bid; item < NI; item += 512) {
    // decode item -> (e, m0, n0)
    int e = NE - 1;
#pragma unroll
    for (int k = NE - 1; k >= 1; k--)
      if (item < mp[k] * 8) e = k - 1;
    int local = item - mp[e] * 8;
    int m0 = (local >> 3) * 256;
    int n0 = (local & 7) * NCOL;
    int cnt = counts[e];
    int bs = base_[e];

    const u16* wb = W + (size_t)e * (FUSED ? (2 * FFNW) * HID : HID * FFNW);

    // ---- stage-unit global addresses for this item ----
    size_t aoffU[2][2], boffU[2][2];
#pragma unroll
    for (int u = 0; u < 2; u++) {
#pragma unroll
      for (int j = 0; j < 2; j++) {
        int rA = qrow + u * 64 + j * 128;
        int clogA = cph ^ (rA & 7);
        int slA = m0 + rA;
        int grA;
        if (FUSED) grA = tokc[bs + (slA < cnt ? slA : 0)];
        else       grA = bs + (slA < cnt ? slA : 0);
        aoffU[u][j] = (size_t)grA * KD + (size_t)clogA * 8;
        int rB = rBl[u][j];
        int clogB = cph ^ (rB & 7);
        int grB = FUSED ? (rB < 128 ? n0 + rB : FFNW + n0 + (rB - 128)) : (n0 + rB);
        boffU[u][j] = (size_t)grB * KD + (size_t)clogB * 8;
      }
    }

    f32x4 acc[8][4];
#pragma unroll
    for (int mi = 0; mi < 8; mi++)
#pragma unroll
      for (int n = 0; n < 4; n++) acc[mi][n] = (f32x4)(0.f);

#define STAGE_A(u, Ts)                                                                 \
    {                                                                                  \
      unsigned db = ((unsigned)(Ts) & 1) * 32768;                                      \
      size_t ko = (size_t)(Ts) * 64;                                                   \
      GLOAD16(A + aoffU[u][0] + ko, &lds[db + adst[u][0]]);                            \
      GLOAD16(A + aoffU[u][1] + ko, &lds[db + adst[u][1]]);                            \
    }
#define STAGE_B(u, Ts)                                                                 \
    {                                                                                  \
      unsigned db = ((unsigned)(Ts) & 1) * 32768;                                      \
      size_t ko = (size_t)(Ts) * 64;                                                   \
      GLOAD16(wb + boffU[u][0] + ko, &lds[db + bdst[u][0]]);                           \
      GLOAD16(wb + boffU[u][1] + ko, &lds[db + bdst[u][1]]);                           \
    }

    // prologue: Am0(0),Bn0(0),Am1(0),Bn1(0),Am0(1),Bn0(1) = 12 loads.
    STAGE_A(0, 0); STAGE_B(0, 0); STAGE_A(1, 0); STAGE_B(1, 0);
    STAGE_A(0, 1); STAGE_B(0, 1);
    VMCNT(4);   // tile 0's 8 oldest loads landed; A0(1),B0(1) may fly
    BAR();

    short8 af[4][2], bn0[2][2], bn1[2][2];

    for (int T = 0; T < NT; ++T) {
      const char* sb = (const char*)lds + ((unsigned)(T & 1)) * 65536;

      // ---- q0: read af(mh0) + bn0; stage Am1(T+1); mfma m0 x n0 ----
#pragma unroll
      for (int mi = 0; mi < 4; mi++)
#pragma unroll
        for (int kk = 0; kk < 2; kk++)
          af[mi][kk] = *(const short8*)(sb + (arow + mi * 16 + frow) * 128 + sw[kk]);
#pragma unroll
      for (int n = 0; n < 2; n++) {
        int rb = FUSED ? (wn * 32 + n * 16 + frow) : (wn * 64 + n * 16 + frow);
#pragma unroll
        for (int kk = 0; kk < 2; kk++)
          bn0[n][kk] = *(const short8*)(sb + 65536 / 2 + rb * 128 + sw[kk]);
      }
      if (T + 1 < NT) STAGE_A(1, T + 1);
      BAR();
      __builtin_amdgcn_s_setprio(1);
#pragma unroll
      for (int mi = 0; mi < 4; mi++)
#pragma unroll
        for (int n = 0; n < 2; n++)
#pragma unroll
          for (int kk = 0; kk < 2; kk++)
            acc[mi][n] = __builtin_amdgcn_mfma_f32_16x16x32_bf16(af[mi][kk], bn0[n][kk], acc[mi][n], 0, 0, 0);
      __builtin_amdgcn_s_setprio(0);
      BAR();

      // ---- q1: read bn1; stage Bn1(T+1); mfma m0 x n1 ----
#pragma unroll
      for (int n = 0; n < 2; n++) {
        int rb = FUSED ? (128 + wn * 32 + n * 16 + frow) : (wn * 64 + 32 + n * 16 + frow);
#pragma unroll
        for (int kk = 0; kk < 2; kk++)
          bn1[n][kk] = *(const short8*)(sb + 65536 / 2 + rb * 128 + sw[kk]);
      }
      if (T + 1 < NT) STAGE_B(1, T + 1);
      BAR();
      __builtin_amdgcn_s_setprio(1);
#pragma unroll
      for (int mi = 0; mi < 4; mi++)
#pragma unroll
        for (int n = 0; n < 2; n++)
#pragma unroll
          for (int kk = 0; kk < 2; kk++)
            acc[mi][n + 2] = __builtin_amdgcn_mfma_f32_16x16x32_bf16(af[mi][kk], bn1[n][kk], acc[mi][n + 2], 0, 0, 0);
      __builtin_amdgcn_s_setprio(0);
      BAR();

      // ---- q2: read af(mh1); stage Am0(T+2); mfma m1 x n0 ----
#pragma unroll
      for (int mi = 0; mi < 4; mi++)
#pragma unroll
        for (int kk = 0; kk < 2; kk++)
          af[mi][kk] = *(const short8*)(sb + (arow + 64 + mi * 16 + frow) * 128 + sw[kk]);
      if (T + 2 < NT) STAGE_A(0, T + 2);
      BAR();
      __builtin_amdgcn_s_setprio(1);
#pragma unroll
      for (int mi = 0; mi < 4; mi++)
#pragma unroll
        for (int n = 0; n < 2; n++)
#pragma unroll
          for (int kk = 0; kk < 2; kk++)
            acc[mi + 4][n] = __builtin_amdgcn_mfma_f32_16x16x32_bf16(af[mi][kk], bn0[n][kk], acc[mi + 4][n], 0, 0, 0);
      __builtin_amdgcn_s_setprio(0);
      BAR();

      // ---- q3: stage Bn0(T+2); mfma m1 x n1; END-OF-TILE landing wait ----
      if (T + 2 < NT) STAGE_B(0, T + 2);
      BAR();
      __builtin_amdgcn_s_setprio(1);
#pragma unroll
      for (int mi = 0; mi < 4; mi++)
#pragma unroll
        for (int n = 0; n < 2; n++)
#pragma unroll
          for (int kk = 0; kk < 2; kk++)
            acc[mi + 4][n + 2] = __builtin_amdgcn_mfma_f32_16x16x32_bf16(af[mi][kk], bn1[n][kk], acc[mi + 4][n + 2], 0, 0, 0);
      __builtin_amdgcn_s_setprio(0);
      if (T < NT - 2) { VMCNT(4); }
      else if (T == NT - 2) { VMCNT(0); }
      BAR();
    }
#undef STAGE_A
#undef STAGE_B

    // epilogue: C/D col=lane&15, row=(lane>>4)*4+r
#pragma unroll
    for (int mi = 0; mi < 8; mi++) {
#pragma unroll
      for (int r = 0; r < 4; r++) {
        int row = arow + mi * 16 + fk * 4 + r;
        int sl = m0 + row;
        if (sl < cnt) {
          if (FUSED) {
            u16* yr = Y + (size_t)(bs + sl) * ND + n0 + wn * 32 + frow;
#pragma unroll
            for (int j = 0; j < 2; j++) {
              float g = acc[mi][j][r];
              float u = acc[mi][j + 2][r];
              float sv = g / (1.f + expf(-g));
              yr[j * 16] = f2bf(sv * u);
            }
          } else {
            u16* yr = Y + (size_t)(bs + sl) * ND + n0 + wn * 64 + frow;
#pragma unroll
            for (int n = 0; n < 4; n++) yr[n * 16] = f2bf(acc[mi][n][r]);
          }
        }
      }
    }
  }
}

// ---------------- combine: out[t] = c0*y[p0] + c1*y[p1] ----------------
__global__ __launch_bounds__(256) void k_combine(const unsigned short* __restrict__ y,
                                                 const int* __restrict__ inv,
                                                 const float* __restrict__ cw,
                                                 float* __restrict__ out) {
  long i = (long)blockIdx.x * 256 + threadIdx.x;
  int t = (int)(i >> 8);
  int c = (int)(i & 255);
  int p0 = inv[2 * t], p1 = inv[2 * t + 1];
  float c0 = cw[2 * t], c1 = cw[2 * t + 1];
  short8 y0 = *(const short8*)(y + (size_t)p0 * HID + c * 8);
  short8 y1 = *(const short8*)(y + (size_t)p1 * HID + c * 8);
  float4 o0, o1;
  o0.x = c0 * bf2f((unsigned short)y0[0]) + c1 * bf2f((unsigned short)y1[0]);
  o0.y = c0 * bf2f((unsigned short)y0[1]) + c1 * bf2f((unsigned short)y1[1]);
  o0.z = c0 * bf2f((unsigned short)y0[2]) + c1 * bf2f((unsigned short)y1[2]);
  o0.w = c0 * bf2f((unsigned short)y0[3]) + c1 * bf2f((unsigned short)y1[3]);
  o1.x = c0 * bf2f((unsigned short)y0[4]) + c1 * bf2f((unsigned short)y1[4]);
  o1.y = c0 * bf2f((unsigned short)y0[5]) + c1 * bf2f((unsigned short)y1[5]);
  o1.z = c0 * bf2f((unsigned short)y0[6]) + c1 * bf2f((unsigned short)y1[6]);
  o1.w = c0 * bf2f((unsigned short)y0[7]) + c1 * bf2f((unsigned short)y1[7]);
  float4* op = (float4*)(out + (size_t)t * HID + c * 8);
  op[0] = o0;
  op[1] = o1;
}

extern "C" void kernel_launch(void* const* d_in, const int* in_sizes, int n_in,
                              void* d_out, int out_size, void* d_ws, size_t ws_size,
                              hipStream_t stream) {
  const float* x   = (const float*)d_in[0];
  const float* gw  = (const float*)d_in[1];
  const float* w13 = (const float*)d_in[2];
  const float* w2  = (const float*)d_in[3];
  float* out = (float*)d_out;
  float* logits = out + (size_t)T_TOK * HID;

  uint8_t* p = (uint8_t*)d_ws;
  unsigned short* xb   = (unsigned short*)p; p += (size_t)T_TOK * HID * 2;
  unsigned short* w13b = (unsigned short*)p; p += (size_t)NE * 2 * FFNW * HID * 2;
  unsigned short* w2b  = (unsigned short*)p; p += (size_t)NE * HID * FFNW * 2;
  unsigned short* act  = (unsigned short*)p; p += (size_t)NPAIR * FFNW * 2;
  unsigned short* y    = (unsigned short*)p; p += (size_t)NPAIR * HID * 2;
  int* sel  = (int*)p;   p += (size_t)NPAIR * 4;
  float* cw = (float*)p; p += (size_t)NPAIR * 4;
  int* tokc = (int*)p;   p += (size_t)NPAIR * 4;
  int* inv  = (int*)p;   p += (size_t)NPAIR * 4;
  u16* lrank = (u16*)p;  p += (size_t)NPAIR * 2;
  int* blkcnt = (int*)p; p += 32 * NE * 4;
  int* counts = (int*)p; p += 256;
  int* base   = (int*)p; p += 256;
  int* mpre   = (int*)p; p += 256;
  if ((size_t)(p - (uint8_t*)d_ws) > ws_size) return;

  k_cast<<<2048, 256, 0, stream>>>(w13, w13b, (long)NE * 2 * FFNW * HID / 8);
  k_cast<<<2048, 256, 0, stream>>>(w2, w2b, (long)NE * HID * FFNW / 8);
  k_router<<<T_TOK / 4, 256, 0, stream>>>(x, gw, xb, logits, sel, cw);
  k_count<<<32, 256, 0, stream>>>(sel, lrank, blkcnt);
  k_scanplace<<<32, 256, 0, stream>>>(sel, lrank, blkcnt, tokc, inv, counts, base, mpre);

  // GEMM1 + fused SwiGLU: act[pair][F]  (flattened items, 512 blocks)
  k_gemm<true, HID, FFNW><<<512, 512, 0, stream>>>(xb, w13b, act, counts, base, tokc, mpre);
  // GEMM2: y[pair][H]
  k_gemm<false, FFNW, HID><<<512, 512, 0, stream>>>(act, w2b, y, counts, base, tokc, mpre);
  // combine into out
  k_combine<<<(int)((long)T_TOK * HID / 8 / 256), 256, 0, stream>>>(y, inv, cw, out);
}

// Round 11
// 364.499 us; speedup vs baseline: 1.0987x; 1.0987x over previous
//
#include <hip/hip_runtime.h>
#include <stdint.h>

typedef short short8 __attribute__((ext_vector_type(8)));
typedef float f32x4 __attribute__((ext_vector_type(4)));
typedef unsigned short u16;

#define T_TOK 8192
#define HID   2048
#define FFNW  1024
#define NE    8
#define NPAIR (2 * T_TOK)

#define VMCNT(n) asm volatile("s_waitcnt vmcnt(" #n ")" ::: "memory")
#define BAR() __builtin_amdgcn_s_barrier()

__device__ __forceinline__ unsigned short f2bf(float f) {
  unsigned int b = __float_as_uint(f);
  b += 0x7fffu + ((b >> 16) & 1u);   // RNE
  return (unsigned short)(b >> 16);
}
__device__ __forceinline__ float bf2f(unsigned short u) {
  return __uint_as_float(((unsigned)u) << 16);
}

#define GLOAD16(gptr, lptr)                                                          \
  __builtin_amdgcn_global_load_lds(                                                  \
      (const __attribute__((address_space(1))) unsigned int*)(gptr),                 \
      (__attribute__((address_space(3))) unsigned int*)(lptr), 16, 0, 0)

// ---------------- cast f32 -> bf16 (8 elems/thread) ----------------
__global__ __launch_bounds__(256) void k_cast(const float* __restrict__ in,
                                              unsigned short* __restrict__ out,
                                              long n8) {
  long i = (long)blockIdx.x * blockDim.x + threadIdx.x;
  long stride = (long)gridDim.x * blockDim.x;
  for (; i < n8; i += stride) {
    const float4* p = (const float4*)(in + i * 8);
    float4 a = p[0], b = p[1];
    uint4 o;
    o.x = (unsigned)f2bf(a.x) | ((unsigned)f2bf(a.y) << 16);
    o.y = (unsigned)f2bf(a.z) | ((unsigned)f2bf(a.w) << 16);
    o.z = (unsigned)f2bf(b.x) | ((unsigned)f2bf(b.y) << 16);
    o.w = (unsigned)f2bf(b.z) | ((unsigned)f2bf(b.w) << 16);
    ((uint4*)out)[i] = o;
  }
}

// ------------- router: wave per token, also emits xb = bf16(x). NO atomics. -------------
__global__ __launch_bounds__(256) void k_router(const float* __restrict__ x,
                                                const float* __restrict__ gw,
                                                unsigned short* __restrict__ xb,
                                                float* __restrict__ logits,
                                                int* __restrict__ sel,
                                                float* __restrict__ cw) {
  int wid = threadIdx.x >> 6, lane = threadIdx.x & 63;
  int t = blockIdx.x * 4 + wid;
  const float4* xr = (const float4*)(x + (size_t)t * HID);
  float acc[NE];
#pragma unroll
  for (int e = 0; e < NE; e++) acc[e] = 0.f;
  for (int i = lane; i < HID / 4; i += 64) {
    float4 xv = xr[i];
    ushort4 o;
    o.x = f2bf(xv.x); o.y = f2bf(xv.y); o.z = f2bf(xv.z); o.w = f2bf(xv.w);
    *(ushort4*)(xb + (size_t)t * HID + i * 4) = o;
#pragma unroll
    for (int e = 0; e < NE; e++) {
      float4 gv = ((const float4*)(gw + (size_t)e * HID))[i];
      acc[e] += xv.x * gv.x + xv.y * gv.y + xv.z * gv.z + xv.w * gv.w;
    }
  }
#pragma unroll
  for (int e = 0; e < NE; e++)
    for (int off = 32; off; off >>= 1) acc[e] += __shfl_down(acc[e], off);
  if (lane == 0) {
    float mx = acc[0];
#pragma unroll
    for (int e = 1; e < NE; e++) mx = fmaxf(mx, acc[e]);
    float p[NE];
#pragma unroll
    for (int e = 0; e < NE; e++) p[e] = expf(acc[e] - mx);
    int i1 = 0; float b1 = p[0];
#pragma unroll
    for (int e = 1; e < NE; e++) if (p[e] > b1) { b1 = p[e]; i1 = e; }
    int i2 = -1; float b2 = -1.f;
#pragma unroll
    for (int e = 0; e < NE; e++) if (e != i1 && p[e] > b2) { b2 = p[e]; i2 = e; }
    float denom = b1 + b2;
#pragma unroll
    for (int e = 0; e < NE; e++) logits[(size_t)t * NE + e] = acc[e];
    sel[2 * t] = i1; sel[2 * t + 1] = i2;
    cw[2 * t] = b1 / denom; cw[2 * t + 1] = b2 / denom;
  }
}

// ------- counting sort, phase 1: per-block ballot multi-split (no atomics) -------
__global__ __launch_bounds__(256) void k_count(const int* __restrict__ sel,
                                               u16* __restrict__ lrank,
                                               int* __restrict__ blkcnt) {
  int blk = blockIdx.x, tid = threadIdx.x;
  int t = blk * 256 + tid;
  int e0 = sel[2 * t], e1 = sel[2 * t + 1];
  int wave = tid >> 6, lane = tid & 63;
  unsigned long long below = (1ull << lane) - 1ull;

  int r0 = 0, r1 = 0, c0[NE], c1[NE];
#pragma unroll
  for (int e = 0; e < NE; e++) {
    unsigned long long m = __ballot(e0 == e);
    if (e == e0) r0 = __popcll(m & below);
    c0[e] = __popcll(m);
  }
#pragma unroll
  for (int e = 0; e < NE; e++) {
    unsigned long long m = __ballot(e1 == e);
    if (e == e1) r1 = __popcll(m & below);
    c1[e] = __popcll(m);
  }

  __shared__ int wcnt[4][NE];
  if (lane < NE) wcnt[wave][lane] = c0[lane] + c1[lane];
  __syncthreads();

  int pre0 = 0, pre1 = 0;
  for (int w = 0; w < wave; w++) { pre0 += wcnt[w][e0]; pre1 += wcnt[w][e1]; }
  lrank[2 * t]     = (u16)(pre0 + r0);
  lrank[2 * t + 1] = (u16)(pre1 + c0[e1] + r1);

  if (tid < NE) {
    int s = 0;
    for (int w = 0; w < 4; w++) s += wcnt[w][tid];
    blkcnt[blk * NE + tid] = s;
  }
}

// ------- counting sort, phase 2: tiny scan (redundant per block) + place -------
__global__ __launch_bounds__(256) void k_scanplace(const int* __restrict__ sel,
                                                   const u16* __restrict__ lrank,
                                                   const int* __restrict__ blkcnt,
                                                   int* __restrict__ tokc,
                                                   int* __restrict__ inv,
                                                   int* __restrict__ counts,
                                                   int* __restrict__ base_) {
  int blk = blockIdx.x, tid = threadIdx.x;
  __shared__ int s_pre[NE], s_tot[NE], s_base[NE + 1];
  if (tid < NE) {
    int run = 0, tot = 0;
    for (int b = 0; b < 32; b++) {
      int c = blkcnt[b * NE + tid];
      if (b < blk) run += c;
      tot += c;
    }
    s_pre[tid] = run;
    s_tot[tid] = tot;
  }
  __syncthreads();
  if (tid == 0) {
    int a = 0;
    for (int e = 0; e < NE; e++) { s_base[e] = a; a += s_tot[e]; }
    s_base[NE] = a;
  }
  __syncthreads();

  int t = blk * 256 + tid;
#pragma unroll
  for (int k = 0; k < 2; k++) {
    int e = sel[2 * t + k];
    int pos = s_base[e] + s_pre[e] + (int)lrank[2 * t + k];
    tokc[pos] = t;
    inv[2 * t + k] = pos;
  }
  if (blk == 0 && tid < NE) {
    counts[tid] = s_tot[tid];
    base_[tid] = s_base[tid];
  }
}

// XCD-aware remap (nwg % 8 == 0): XCD gets a contiguous chunk -> expert locality.
__device__ __forceinline__ int xcd_remap(int L, int nwg) {
  return (L & 7) * (nwg >> 3) + (L >> 3);
}

// ====== 8-phase MFMA GEMM, 2-blocks/CU variant: 128 rows x 128 B-rows, 4 waves ======
// 256 threads (2M x 2N waves, wave-tile 64x64), BK=64, 2 dbufs = 64 KiB LDS ->
// TWO blocks co-resident per CU (independent barrier domains overlap; m114).
// Schedule identical to proven r8: per tile 4 quadrant phases
// {ds_read subtile; stage unit (2 gloads); BAR; setprio+8 MFMA; BAR}.
// Units: A0={rows 0-31,64-95}, A1=+32 (q0/q2 readers); B0/B1 analogous.
// Stage lag: T q0:A1(T+1), q1:B1(T+1), q2:A0(T+2), q3:B0(T+2);
// end-of-tile VMCNT(4) -> tile T+1 fully landed (only T+2's 4 loads younger);
// VMCNT(0) at T==NT-2; prologue {tile0 x4, A0/B0(1)} + VMCNT(4) + BAR.
// XOR chunk-swizzle (chunk ^ row&7) both sides: 0 bank conflicts (measured r2-r10).
template<bool FUSED, int KD, int ND>
__global__ __launch_bounds__(256, 2) void k_gemm(const u16* __restrict__ A,
                                                 const u16* __restrict__ W,
                                                 u16* __restrict__ Y,
                                                 const int* __restrict__ counts,
                                                 const int* __restrict__ base_,
                                                 const int* __restrict__ tokc) {
  int Wk = xcd_remap(blockIdx.x, 4096);
  int e = Wk >> 9;
  int rem = Wk & 511;
  int bx = rem >> 4, by = rem & 15;   // 32 m-blocks x 16 n-blocks

  int cnt = counts[e];
  int m0 = bx * 128;
  if (m0 >= cnt) return;
  constexpr int NCOL = FUSED ? 64 : 128;
  int n0 = by * NCOL;
  int bs = base_[e];

  __shared__ u16 lds[2 * 16384];   // 2 dbufs x 32KB: A[128][64] @0, B[128][64] @8192 (u16 idx)

  int tid = threadIdx.x;
  int wave = tid >> 6, lane = tid & 63;

  const u16* wb = W + (size_t)e * (FUSED ? (2 * FFNW) * HID : HID * FFNW);

  // ---- stage-unit addresses: units u={0,1}, 2 loads j={0,1} each ----
  size_t aoffU[2][2], boffU[2][2];
  unsigned adst[2][2], bdst[2][2];
#pragma unroll
  for (int u = 0; u < 2; u++) {
#pragma unroll
    for (int j = 0; j < 2; j++) {
      int slot = j * 256 + tid;
      int q = slot >> 3, cph = slot & 7;
      int rA = (q & 31) + (q >> 5) * 64 + u * 32;   // A0={0-31,64-95}, A1=+32
      int clogA = cph ^ (rA & 7);
      int slA = m0 + rA;
      int grA;
      if (FUSED) grA = tokc[bs + (slA < cnt ? slA : 0)];
      else       grA = bs + (slA < cnt ? slA : 0);
      aoffU[u][j] = (size_t)grA * KD + (size_t)clogA * 8;
      adst[u][j] = (unsigned)(rA * 64 + cph * 8);
      int rB;
      if (FUSED) rB = q + u * 64;                              // B0=0-63(g), B1=64-127(u)
      else       rB = (q & 31) + (q >> 5) * 64 + u * 32;       // B0={0-31,64-95}, B1=+32
      int clogB = cph ^ (rB & 7);
      int grB = FUSED ? (rB < 64 ? n0 + rB : FFNW + n0 + (rB - 64)) : (n0 + rB);
      boffU[u][j] = (size_t)grB * KD + (size_t)clogB * 8;
      bdst[u][j] = (unsigned)(8192 + rB * 64 + cph * 8);
    }
  }

  f32x4 acc[4][4];
#pragma unroll
  for (int mi = 0; mi < 4; mi++)
#pragma unroll
    for (int n = 0; n < 4; n++) acc[mi][n] = (f32x4)(0.f);

  int wm = wave >> 1, wn = wave & 1;   // 2M x 2N
  int arow = wm * 64;
  int frow = lane & 15, fk = lane >> 4;
  int sw[2];
  sw[0] = ((fk) ^ (frow & 7)) << 4;
  sw[1] = ((fk + 4) ^ (frow & 7)) << 4;

  constexpr int NT = KD / 64;

#define STAGE_A(u, Ts)                                                                 \
  {                                                                                    \
    unsigned db = ((unsigned)(Ts) & 1) * 16384;                                        \
    size_t ko = (size_t)(Ts) * 64;                                                     \
    GLOAD16(A + aoffU[u][0] + ko, &lds[db + adst[u][0]]);                              \
    GLOAD16(A + aoffU[u][1] + ko, &lds[db + adst[u][1]]);                              \
  }
#define STAGE_B(u, Ts)                                                                 \
  {                                                                                    \
    unsigned db = ((unsigned)(Ts) & 1) * 16384;                                        \
    size_t ko = (size_t)(Ts) * 64;                                                     \
    GLOAD16(wb + boffU[u][0] + ko, &lds[db + bdst[u][0]]);                             \
    GLOAD16(wb + boffU[u][1] + ko, &lds[db + bdst[u][1]]);                             \
  }

  // prologue: A0(0),B0(0),A1(0),B1(0),A0(1),B0(1) = 12 loads.
  STAGE_A(0, 0); STAGE_B(0, 0); STAGE_A(1, 0); STAGE_B(1, 0);
  STAGE_A(0, 1); STAGE_B(0, 1);
  VMCNT(4);   // tile 0's 8 oldest loads landed; A0(1),B0(1) may fly
  BAR();

  short8 af[2][2], bn0[2][2], bn1[2][2];

  for (int T = 0; T < NT; ++T) {
    const char* sb = (const char*)lds + ((unsigned)(T & 1)) * 32768;

    // ---- q0: read af(mh0) + bn0; stage A1(T+1); mfma m0 x n0 ----
#pragma unroll
    for (int mi = 0; mi < 2; mi++)
#pragma unroll
      for (int kk = 0; kk < 2; kk++)
        af[mi][kk] = *(const short8*)(sb + (arow + mi * 16 + frow) * 128 + sw[kk]);
#pragma unroll
    for (int n = 0; n < 2; n++) {
      int rb = FUSED ? (wn * 32 + n * 16 + frow) : (wn * 64 + n * 16 + frow);
#pragma unroll
      for (int kk = 0; kk < 2; kk++)
        bn0[n][kk] = *(const short8*)(sb + 16384 + rb * 128 + sw[kk]);
    }
    if (T + 1 < NT) STAGE_A(1, T + 1);
    BAR();
    __builtin_amdgcn_s_setprio(1);
#pragma unroll
    for (int mi = 0; mi < 2; mi++)
#pragma unroll
      for (int n = 0; n < 2; n++)
#pragma unroll
        for (int kk = 0; kk < 2; kk++)
          acc[mi][n] = __builtin_amdgcn_mfma_f32_16x16x32_bf16(af[mi][kk], bn0[n][kk], acc[mi][n], 0, 0, 0);
    __builtin_amdgcn_s_setprio(0);
    BAR();

    // ---- q1: read bn1; stage B1(T+1); mfma m0 x n1 ----
#pragma unroll
    for (int n = 0; n < 2; n++) {
      int rb = FUSED ? (64 + wn * 32 + n * 16 + frow) : (wn * 64 + 32 + n * 16 + frow);
#pragma unroll
      for (int kk = 0; kk < 2; kk++)
        bn1[n][kk] = *(const short8*)(sb + 16384 + rb * 128 + sw[kk]);
    }
    if (T + 1 < NT) STAGE_B(1, T + 1);
    BAR();
    __builtin_amdgcn_s_setprio(1);
#pragma unroll
    for (int mi = 0; mi < 2; mi++)
#pragma unroll
      for (int n = 0; n < 2; n++)
#pragma unroll
        for (int kk = 0; kk < 2; kk++)
          acc[mi][n + 2] = __builtin_amdgcn_mfma_f32_16x16x32_bf16(af[mi][kk], bn1[n][kk], acc[mi][n + 2], 0, 0, 0);
    __builtin_amdgcn_s_setprio(0);
    BAR();

    // ---- q2: read af(mh1); stage A0(T+2); mfma m1 x n0 ----
#pragma unroll
    for (int mi = 0; mi < 2; mi++)
#pragma unroll
      for (int kk = 0; kk < 2; kk++)
        af[mi][kk] = *(const short8*)(sb + (arow + 32 + mi * 16 + frow) * 128 + sw[kk]);
    if (T + 2 < NT) STAGE_A(0, T + 2);
    BAR();
    __builtin_amdgcn_s_setprio(1);
#pragma unroll
    for (int mi = 0; mi < 2; mi++)
#pragma unroll
      for (int n = 0; n < 2; n++)
#pragma unroll
        for (int kk = 0; kk < 2; kk++)
          acc[mi + 2][n] = __builtin_amdgcn_mfma_f32_16x16x32_bf16(af[mi][kk], bn0[n][kk], acc[mi + 2][n], 0, 0, 0);
    __builtin_amdgcn_s_setprio(0);
    BAR();

    // ---- q3: stage B0(T+2); mfma m1 x n1; END-OF-TILE landing wait ----
    if (T + 2 < NT) STAGE_B(0, T + 2);
    BAR();
    __builtin_amdgcn_s_setprio(1);
#pragma unroll
    for (int mi = 0; mi < 2; mi++)
#pragma unroll
      for (int n = 0; n < 2; n++)
#pragma unroll
        for (int kk = 0; kk < 2; kk++)
          acc[mi + 2][n + 2] = __builtin_amdgcn_mfma_f32_16x16x32_bf16(af[mi][kk], bn1[n][kk], acc[mi + 2][n + 2], 0, 0, 0);
    __builtin_amdgcn_s_setprio(0);
    if (T < NT - 2) { VMCNT(4); }
    else if (T == NT - 2) { VMCNT(0); }
    BAR();
  }
#undef STAGE_A
#undef STAGE_B

  // epilogue: C/D col=lane&15, row=(lane>>4)*4+r
#pragma unroll
  for (int mi = 0; mi < 4; mi++) {
#pragma unroll
    for (int r = 0; r < 4; r++) {
      int row = arow + (mi >> 1) * 32 + (mi & 1) * 16 + fk * 4 + r;
      int sl = m0 + row;
      if (sl < cnt) {
        if (FUSED) {
          u16* yr = Y + (size_t)(bs + sl) * ND + n0 + wn * 32 + frow;
#pragma unroll
          for (int j = 0; j < 2; j++) {
            float g = acc[mi][j][r];
            float u = acc[mi][j + 2][r];
            float sv = g / (1.f + expf(-g));
            yr[j * 16] = f2bf(sv * u);
          }
        } else {
          u16* yr = Y + (size_t)(bs + sl) * ND + n0 + wn * 64 + frow;
#pragma unroll
          for (int n = 0; n < 4; n++) yr[n * 16] = f2bf(acc[mi][n][r]);
        }
      }
    }
  }
}

// ---------------- combine: out[t] = c0*y[p0] + c1*y[p1] ----------------
__global__ __launch_bounds__(256) void k_combine(const unsigned short* __restrict__ y,
                                                 const int* __restrict__ inv,
                                                 const float* __restrict__ cw,
                                                 float* __restrict__ out) {
  long i = (long)blockIdx.x * 256 + threadIdx.x;
  int t = (int)(i >> 8);
  int c = (int)(i & 255);
  int p0 = inv[2 * t], p1 = inv[2 * t + 1];
  float c0 = cw[2 * t], c1 = cw[2 * t + 1];
  short8 y0 = *(const short8*)(y + (size_t)p0 * HID + c * 8);
  short8 y1 = *(const short8*)(y + (size_t)p1 * HID + c * 8);
  float4 o0, o1;
  o0.x = c0 * bf2f((unsigned short)y0[0]) + c1 * bf2f((unsigned short)y1[0]);
  o0.y = c0 * bf2f((unsigned short)y0[1]) + c1 * bf2f((unsigned short)y1[1]);
  o0.z = c0 * bf2f((unsigned short)y0[2]) + c1 * bf2f((unsigned short)y1[2]);
  o0.w = c0 * bf2f((unsigned short)y0[3]) + c1 * bf2f((unsigned short)y1[3]);
  o1.x = c0 * bf2f((unsigned short)y0[4]) + c1 * bf2f((unsigned short)y1[4]);
  o1.y = c0 * bf2f((unsigned short)y0[5]) + c1 * bf2f((unsigned short)y1[5]);
  o1.z = c0 * bf2f((unsigned short)y0[6]) + c1 * bf2f((unsigned short)y1[6]);
  o1.w = c0 * bf2f((unsigned short)y0[7]) + c1 * bf2f((unsigned short)y1[7]);
  float4* op = (float4*)(out + (size_t)t * HID + c * 8);
  op[0] = o0;
  op[1] = o1;
}

extern "C" void kernel_launch(void* const* d_in, const int* in_sizes, int n_in,
                              void* d_out, int out_size, void* d_ws, size_t ws_size,
                              hipStream_t stream) {
  const float* x   = (const float*)d_in[0];
  const float* gw  = (const float*)d_in[1];
  const float* w13 = (const float*)d_in[2];
  const float* w2  = (const float*)d_in[3];
  float* out = (float*)d_out;
  float* logits = out + (size_t)T_TOK * HID;

  uint8_t* p = (uint8_t*)d_ws;
  unsigned short* xb   = (unsigned short*)p; p += (size_t)T_TOK * HID * 2;
  unsigned short* w13b = (unsigned short*)p; p += (size_t)NE * 2 * FFNW * HID * 2;
  unsigned short* w2b  = (unsigned short*)p; p += (size_t)NE * HID * FFNW * 2;
  unsigned short* act  = (unsigned short*)p; p += (size_t)NPAIR * FFNW * 2;
  unsigned short* y    = (unsigned short*)p; p += (size_t)NPAIR * HID * 2;
  int* sel  = (int*)p;   p += (size_t)NPAIR * 4;
  float* cw = (float*)p; p += (size_t)NPAIR * 4;
  int* tokc = (int*)p;   p += (size_t)NPAIR * 4;
  int* inv  = (int*)p;   p += (size_t)NPAIR * 4;
  u16* lrank = (u16*)p;  p += (size_t)NPAIR * 2;
  int* blkcnt = (int*)p; p += 32 * NE * 4;
  int* counts = (int*)p; p += 256;
  int* base   = (int*)p; p += 256;
  if ((size_t)(p - (uint8_t*)d_ws) > ws_size) return;

  k_cast<<<2048, 256, 0, stream>>>(w13, w13b, (long)NE * 2 * FFNW * HID / 8);
  k_cast<<<2048, 256, 0, stream>>>(w2, w2b, (long)NE * HID * FFNW / 8);
  k_router<<<T_TOK / 4, 256, 0, stream>>>(x, gw, xb, logits, sel, cw);
  k_count<<<32, 256, 0, stream>>>(sel, lrank, blkcnt);
  k_scanplace<<<32, 256, 0, stream>>>(sel, lrank, blkcnt, tokc, inv, counts, base);

  // GEMM1 + fused SwiGLU: act[pair][F]  (128 rows x 64 act-cols per block, 2 blk/CU)
  k_gemm<true, HID, FFNW><<<4096, 256, 0, stream>>>(xb, w13b, act, counts, base, tokc);
  // GEMM2: y[pair][H]  (128 rows x 128 cols per block, 2 blk/CU)
  k_gemm<false, FFNW, HID><<<4096, 256, 0, stream>>>(act, w2b, y, counts, base, tokc);
  // combine into out
  k_combine<<<(int)((long)T_TOK * HID / 8 / 256), 256, 0, stream>>>(y, inv, cw, out);
}

// Round 12
// 359.695 us; speedup vs baseline: 1.1134x; 1.0134x over previous
//
#include <hip/hip_runtime.h>
#include <stdint.h>

typedef short short8 __attribute__((ext_vector_type(8)));
typedef float f32x4 __attribute__((ext_vector_type(4)));
typedef float f32x4v __attribute__((ext_vector_type(4)));
typedef unsigned short u16;

#define T_TOK 8192
#define HID   2048
#define FFNW  1024
#define NE    8
#define NPAIR (2 * T_TOK)

#define VMCNT(n) asm volatile("s_waitcnt vmcnt(" #n ")" ::: "memory")
#define BAR() __builtin_amdgcn_s_barrier()

__device__ __forceinline__ unsigned short f2bf(float f) {
  unsigned int b = __float_as_uint(f);
  b += 0x7fffu + ((b >> 16) & 1u);   // RNE
  return (unsigned short)(b >> 16);
}
__device__ __forceinline__ float bf2f(unsigned short u) {
  return __uint_as_float(((unsigned)u) << 16);
}

#define GLOAD16(gptr, lptr)                                                          \
  __builtin_amdgcn_global_load_lds(                                                  \
      (const __attribute__((address_space(1))) unsigned int*)(gptr),                 \
      (__attribute__((address_space(3))) unsigned int*)(lptr), 16, 0, 0)

// ------- cast f32 -> bf16 (8 elems/thread); NT source reads keep L3 clean -------
__global__ __launch_bounds__(256) void k_cast(const float* __restrict__ in,
                                              unsigned short* __restrict__ out,
                                              long n8) {
  long i = (long)blockIdx.x * blockDim.x + threadIdx.x;
  long stride = (long)gridDim.x * blockDim.x;
  for (; i < n8; i += stride) {
    const f32x4v* p = (const f32x4v*)(in + i * 8);
    f32x4v a = __builtin_nontemporal_load(p);
    f32x4v b = __builtin_nontemporal_load(p + 1);
    uint4 o;
    o.x = (unsigned)f2bf(a[0]) | ((unsigned)f2bf(a[1]) << 16);
    o.y = (unsigned)f2bf(a[2]) | ((unsigned)f2bf(a[3]) << 16);
    o.z = (unsigned)f2bf(b[0]) | ((unsigned)f2bf(b[1]) << 16);
    o.w = (unsigned)f2bf(b[2]) | ((unsigned)f2bf(b[3]) << 16);
    ((uint4*)out)[i] = o;
  }
}

// ------------- router: wave per token, also emits xb = bf16(x). NO atomics. -------------
__global__ __launch_bounds__(256) void k_router(const float* __restrict__ x,
                                                const float* __restrict__ gw,
                                                unsigned short* __restrict__ xb,
                                                float* __restrict__ logits,
                                                int* __restrict__ sel,
                                                float* __restrict__ cw) {
  int wid = threadIdx.x >> 6, lane = threadIdx.x & 63;
  int t = blockIdx.x * 4 + wid;
  const f32x4v* xr = (const f32x4v*)(x + (size_t)t * HID);
  float acc[NE];
#pragma unroll
  for (int e = 0; e < NE; e++) acc[e] = 0.f;
  for (int i = lane; i < HID / 4; i += 64) {
    f32x4v xv = __builtin_nontemporal_load(xr + i);   // one-shot: don't pollute L3
    ushort4 o;
    o.x = f2bf(xv[0]); o.y = f2bf(xv[1]); o.z = f2bf(xv[2]); o.w = f2bf(xv[3]);
    *(ushort4*)(xb + (size_t)t * HID + i * 4) = o;
#pragma unroll
    for (int e = 0; e < NE; e++) {
      f32x4v gv = ((const f32x4v*)(gw + (size_t)e * HID))[i];   // reused: keep cached
      acc[e] += xv[0] * gv[0] + xv[1] * gv[1] + xv[2] * gv[2] + xv[3] * gv[3];
    }
  }
#pragma unroll
  for (int e = 0; e < NE; e++)
    for (int off = 32; off; off >>= 1) acc[e] += __shfl_down(acc[e], off);
  if (lane == 0) {
    float mx = acc[0];
#pragma unroll
    for (int e = 1; e < NE; e++) mx = fmaxf(mx, acc[e]);
    float p[NE];
#pragma unroll
    for (int e = 0; e < NE; e++) p[e] = expf(acc[e] - mx);
    int i1 = 0; float b1 = p[0];
#pragma unroll
    for (int e = 1; e < NE; e++) if (p[e] > b1) { b1 = p[e]; i1 = e; }
    int i2 = -1; float b2 = -1.f;
#pragma unroll
    for (int e = 0; e < NE; e++) if (e != i1 && p[e] > b2) { b2 = p[e]; i2 = e; }
    float denom = b1 + b2;
#pragma unroll
    for (int e = 0; e < NE; e++) logits[(size_t)t * NE + e] = acc[e];
    sel[2 * t] = i1; sel[2 * t + 1] = i2;
    cw[2 * t] = b1 / denom; cw[2 * t + 1] = b2 / denom;
  }
}

// ------- counting sort, phase 1: per-block ballot multi-split (no atomics) -------
__global__ __launch_bounds__(256) void k_count(const int* __restrict__ sel,
                                               u16* __restrict__ lrank,
                                               int* __restrict__ blkcnt) {
  int blk = blockIdx.x, tid = threadIdx.x;
  int t = blk * 256 + tid;
  int e0 = sel[2 * t], e1 = sel[2 * t + 1];
  int wave = tid >> 6, lane = tid & 63;
  unsigned long long below = (1ull << lane) - 1ull;

  int r0 = 0, r1 = 0, c0[NE], c1[NE];
#pragma unroll
  for (int e = 0; e < NE; e++) {
    unsigned long long m = __ballot(e0 == e);
    if (e == e0) r0 = __popcll(m & below);
    c0[e] = __popcll(m);
  }
#pragma unroll
  for (int e = 0; e < NE; e++) {
    unsigned long long m = __ballot(e1 == e);
    if (e == e1) r1 = __popcll(m & below);
    c1[e] = __popcll(m);
  }

  __shared__ int wcnt[4][NE];
  if (lane < NE) wcnt[wave][lane] = c0[lane] + c1[lane];
  __syncthreads();

  int pre0 = 0, pre1 = 0;
  for (int w = 0; w < wave; w++) { pre0 += wcnt[w][e0]; pre1 += wcnt[w][e1]; }
  lrank[2 * t]     = (u16)(pre0 + r0);
  lrank[2 * t + 1] = (u16)(pre1 + c0[e1] + r1);

  if (tid < NE) {
    int s = 0;
    for (int w = 0; w < 4; w++) s += wcnt[w][tid];
    blkcnt[blk * NE + tid] = s;
  }
}

// ------- counting sort, phase 2: tiny scan (redundant per block) + place -------
__global__ __launch_bounds__(256) void k_scanplace(const int* __restrict__ sel,
                                                   const u16* __restrict__ lrank,
                                                   const int* __restrict__ blkcnt,
                                                   int* __restrict__ tokc,
                                                   int* __restrict__ inv,
                                                   int* __restrict__ counts,
                                                   int* __restrict__ base_) {
  int blk = blockIdx.x, tid = threadIdx.x;
  __shared__ int s_pre[NE], s_tot[NE], s_base[NE + 1];
  if (tid < NE) {
    int run = 0, tot = 0;
    for (int b = 0; b < 32; b++) {
      int c = blkcnt[b * NE + tid];
      if (b < blk) run += c;
      tot += c;
    }
    s_pre[tid] = run;
    s_tot[tid] = tot;
  }
  __syncthreads();
  if (tid == 0) {
    int a = 0;
    for (int e = 0; e < NE; e++) { s_base[e] = a; a += s_tot[e]; }
    s_base[NE] = a;
  }
  __syncthreads();

  int t = blk * 256 + tid;
#pragma unroll
  for (int k = 0; k < 2; k++) {
    int e = sel[2 * t + k];
    int pos = s_base[e] + s_pre[e] + (int)lrank[2 * t + k];
    tokc[pos] = t;
    inv[2 * t + k] = pos;
  }
  if (blk == 0 && tid < NE) {
    counts[tid] = s_tot[tid];
    base_[tid] = s_base[tid];
  }
}

// XCD-aware remap (nwg % 8 == 0): XCD gets a contiguous chunk -> expert locality.
__device__ __forceinline__ int xcd_remap(int L, int nwg) {
  return (L & 7) * (nwg >> 3) + (L >> 3);
}

// ====== 8-phase MFMA GEMM, 2-blocks/CU: 128 rows x 128 B-rows, 4 waves ======
// (proven r11 schedule, unchanged). Within-XCD order now BY-OUTER so the ~64
// co-resident blocks of an XCD share 1-2 B-panels (<=1MB, fits 4MB L2).
template<bool FUSED, int KD, int ND>
__global__ __launch_bounds__(256, 2) void k_gemm(const u16* __restrict__ A,
                                                 const u16* __restrict__ W,
                                                 u16* __restrict__ Y,
                                                 const int* __restrict__ counts,
                                                 const int* __restrict__ base_,
                                                 const int* __restrict__ tokc) {
  int Wk = xcd_remap(blockIdx.x, 4096);
  int e = Wk >> 9;
  int rem = Wk & 511;
  int by = rem >> 5, bx = rem & 31;   // by-outer: concurrent blocks share B panels

  int cnt = counts[e];
  int m0 = bx * 128;
  if (m0 >= cnt) return;
  constexpr int NCOL = FUSED ? 64 : 128;
  int n0 = by * NCOL;
  int bs = base_[e];

  __shared__ u16 lds[2 * 16384];   // 2 dbufs x 32KB: A[128][64] @0, B[128][64] @8192 (u16 idx)

  int tid = threadIdx.x;
  int wave = tid >> 6, lane = tid & 63;

  const u16* wb = W + (size_t)e * (FUSED ? (2 * FFNW) * HID : HID * FFNW);

  // ---- stage-unit addresses: units u={0,1}, 2 loads j={0,1} each ----
  size_t aoffU[2][2], boffU[2][2];
  unsigned adst[2][2], bdst[2][2];
#pragma unroll
  for (int u = 0; u < 2; u++) {
#pragma unroll
    for (int j = 0; j < 2; j++) {
      int slot = j * 256 + tid;
      int q = slot >> 3, cph = slot & 7;
      int rA = (q & 31) + (q >> 5) * 64 + u * 32;   // A0={0-31,64-95}, A1=+32
      int clogA = cph ^ (rA & 7);
      int slA = m0 + rA;
      int grA;
      if (FUSED) grA = tokc[bs + (slA < cnt ? slA : 0)];
      else       grA = bs + (slA < cnt ? slA : 0);
      aoffU[u][j] = (size_t)grA * KD + (size_t)clogA * 8;
      adst[u][j] = (unsigned)(rA * 64 + cph * 8);
      int rB;
      if (FUSED) rB = q + u * 64;                              // B0=0-63(g), B1=64-127(u)
      else       rB = (q & 31) + (q >> 5) * 64 + u * 32;       // B0={0-31,64-95}, B1=+32
      int clogB = cph ^ (rB & 7);
      int grB = FUSED ? (rB < 64 ? n0 + rB : FFNW + n0 + (rB - 64)) : (n0 + rB);
      boffU[u][j] = (size_t)grB * KD + (size_t)clogB * 8;
      bdst[u][j] = (unsigned)(8192 + rB * 64 + cph * 8);
    }
  }

  f32x4 acc[4][4];
#pragma unroll
  for (int mi = 0; mi < 4; mi++)
#pragma unroll
    for (int n = 0; n < 4; n++) acc[mi][n] = (f32x4)(0.f);

  int wm = wave >> 1, wn = wave & 1;   // 2M x 2N
  int arow = wm * 64;
  int frow = lane & 15, fk = lane >> 4;
  int sw[2];
  sw[0] = ((fk) ^ (frow & 7)) << 4;
  sw[1] = ((fk + 4) ^ (frow & 7)) << 4;

  constexpr int NT = KD / 64;

#define STAGE_A(u, Ts)                                                                 \
  {                                                                                    \
    unsigned db = ((unsigned)(Ts) & 1) * 16384;                                        \
    size_t ko = (size_t)(Ts) * 64;                                                     \
    GLOAD16(A + aoffU[u][0] + ko, &lds[db + adst[u][0]]);                              \
    GLOAD16(A + aoffU[u][1] + ko, &lds[db + adst[u][1]]);                              \
  }
#define STAGE_B(u, Ts)                                                                 \
  {                                                                                    \
    unsigned db = ((unsigned)(Ts) & 1) * 16384;                                        \
    size_t ko = (size_t)(Ts) * 64;                                                     \
    GLOAD16(wb + boffU[u][0] + ko, &lds[db + bdst[u][0]]);                             \
    GLOAD16(wb + boffU[u][1] + ko, &lds[db + bdst[u][1]]);                             \
  }

  // prologue: A0(0),B0(0),A1(0),B1(0),A0(1),B0(1) = 12 loads.
  STAGE_A(0, 0); STAGE_B(0, 0); STAGE_A(1, 0); STAGE_B(1, 0);
  STAGE_A(0, 1); STAGE_B(0, 1);
  VMCNT(4);   // tile 0's 8 oldest loads landed; A0(1),B0(1) may fly
  BAR();

  short8 af[2][2], bn0[2][2], bn1[2][2];

  for (int T = 0; T < NT; ++T) {
    const char* sb = (const char*)lds + ((unsigned)(T & 1)) * 32768;

    // ---- q0: read af(mh0) + bn0; stage A1(T+1); mfma m0 x n0 ----
#pragma unroll
    for (int mi = 0; mi < 2; mi++)
#pragma unroll
      for (int kk = 0; kk < 2; kk++)
        af[mi][kk] = *(const short8*)(sb + (arow + mi * 16 + frow) * 128 + sw[kk]);
#pragma unroll
    for (int n = 0; n < 2; n++) {
      int rb = FUSED ? (wn * 32 + n * 16 + frow) : (wn * 64 + n * 16 + frow);
#pragma unroll
      for (int kk = 0; kk < 2; kk++)
        bn0[n][kk] = *(const short8*)(sb + 16384 + rb * 128 + sw[kk]);
    }
    if (T + 1 < NT) STAGE_A(1, T + 1);
    BAR();
    __builtin_amdgcn_s_setprio(1);
#pragma unroll
    for (int mi = 0; mi < 2; mi++)
#pragma unroll
      for (int n = 0; n < 2; n++)
#pragma unroll
        for (int kk = 0; kk < 2; kk++)
          acc[mi][n] = __builtin_amdgcn_mfma_f32_16x16x32_bf16(af[mi][kk], bn0[n][kk], acc[mi][n], 0, 0, 0);
    __builtin_amdgcn_s_setprio(0);
    BAR();

    // ---- q1: read bn1; stage B1(T+1); mfma m0 x n1 ----
#pragma unroll
    for (int n = 0; n < 2; n++) {
      int rb = FUSED ? (64 + wn * 32 + n * 16 + frow) : (wn * 64 + 32 + n * 16 + frow);
#pragma unroll
      for (int kk = 0; kk < 2; kk++)
        bn1[n][kk] = *(const short8*)(sb + 16384 + rb * 128 + sw[kk]);
    }
    if (T + 1 < NT) STAGE_B(1, T + 1);
    BAR();
    __builtin_amdgcn_s_setprio(1);
#pragma unroll
    for (int mi = 0; mi < 2; mi++)
#pragma unroll
      for (int n = 0; n < 2; n++)
#pragma unroll
        for (int kk = 0; kk < 2; kk++)
          acc[mi][n + 2] = __builtin_amdgcn_mfma_f32_16x16x32_bf16(af[mi][kk], bn1[n][kk], acc[mi][n + 2], 0, 0, 0);
    __builtin_amdgcn_s_setprio(0);
    BAR();

    // ---- q2: read af(mh1); stage A0(T+2); mfma m1 x n0 ----
#pragma unroll
    for (int mi = 0; mi < 2; mi++)
#pragma unroll
      for (int kk = 0; kk < 2; kk++)
        af[mi][kk] = *(const short8*)(sb + (arow + 32 + mi * 16 + frow) * 128 + sw[kk]);
    if (T + 2 < NT) STAGE_A(0, T + 2);
    BAR();
    __builtin_amdgcn_s_setprio(1);
#pragma unroll
    for (int mi = 0; mi < 2; mi++)
#pragma unroll
      for (int n = 0; n < 2; n++)
#pragma unroll
        for (int kk = 0; kk < 2; kk++)
          acc[mi + 2][n] = __builtin_amdgcn_mfma_f32_16x16x32_bf16(af[mi][kk], bn0[n][kk], acc[mi + 2][n], 0, 0, 0);
    __builtin_amdgcn_s_setprio(0);
    BAR();

    // ---- q3: stage B0(T+2); mfma m1 x n1; END-OF-TILE landing wait ----
    if (T + 2 < NT) STAGE_B(0, T + 2);
    BAR();
    __builtin_amdgcn_s_setprio(1);
#pragma unroll
    for (int mi = 0; mi < 2; mi++)
#pragma unroll
      for (int n = 0; n < 2; n++)
#pragma unroll
        for (int kk = 0; kk < 2; kk++)
          acc[mi + 2][n + 2] = __builtin_amdgcn_mfma_f32_16x16x32_bf16(af[mi][kk], bn1[n][kk], acc[mi + 2][n + 2], 0, 0, 0);
    __builtin_amdgcn_s_setprio(0);
    if (T < NT - 2) { VMCNT(4); }
    else if (T == NT - 2) { VMCNT(0); }
    BAR();
  }
#undef STAGE_A
#undef STAGE_B

  // epilogue: C/D col=lane&15, row=(lane>>4)*4+r
#pragma unroll
  for (int mi = 0; mi < 4; mi++) {
#pragma unroll
    for (int r = 0; r < 4; r++) {
      int row = arow + (mi >> 1) * 32 + (mi & 1) * 16 + fk * 4 + r;
      int sl = m0 + row;
      if (sl < cnt) {
        if (FUSED) {
          u16* yr = Y + (size_t)(bs + sl) * ND + n0 + wn * 32 + frow;
#pragma unroll
          for (int j = 0; j < 2; j++) {
            float g = acc[mi][j][r];
            float u = acc[mi][j + 2][r];
            float sv = g / (1.f + expf(-g));
            yr[j * 16] = f2bf(sv * u);
          }
        } else {
          u16* yr = Y + (size_t)(bs + sl) * ND + n0 + wn * 64 + frow;
#pragma unroll
          for (int n = 0; n < 4; n++) yr[n * 16] = f2bf(acc[mi][n][r]);
        }
      }
    }
  }
}

// ---------------- combine: out[t] = c0*y[p0] + c1*y[p1] ----------------
__global__ __launch_bounds__(256) void k_combine(const unsigned short* __restrict__ y,
                                                 const int* __restrict__ inv,
                                                 const float* __restrict__ cw,
                                                 float* __restrict__ out) {
  long i = (long)blockIdx.x * 256 + threadIdx.x;
  int t = (int)(i >> 8);
  int c = (int)(i & 255);
  int p0 = inv[2 * t], p1 = inv[2 * t + 1];
  float c0 = cw[2 * t], c1 = cw[2 * t + 1];
  short8 y0 = *(const short8*)(y + (size_t)p0 * HID + c * 8);
  short8 y1 = *(const short8*)(y + (size_t)p1 * HID + c * 8);
  float4 o0, o1;
  o0.x = c0 * bf2f((unsigned short)y0[0]) + c1 * bf2f((unsigned short)y1[0]);
  o0.y = c0 * bf2f((unsigned short)y0[1]) + c1 * bf2f((unsigned short)y1[1]);
  o0.z = c0 * bf2f((unsigned short)y0[2]) + c1 * bf2f((unsigned short)y1[2]);
  o0.w = c0 * bf2f((unsigned short)y0[3]) + c1 * bf2f((unsigned short)y1[3]);
  o1.x = c0 * bf2f((unsigned short)y0[4]) + c1 * bf2f((unsigned short)y1[4]);
  o1.y = c0 * bf2f((unsigned short)y0[5]) + c1 * bf2f((unsigned short)y1[5]);
  o1.z = c0 * bf2f((unsigned short)y0[6]) + c1 * bf2f((unsigned short)y1[6]);
  o1.w = c0 * bf2f((unsigned short)y0[7]) + c1 * bf2f((unsigned short)y1[7]);
  float4* op = (float4*)(out + (size_t)t * HID + c * 8);
  op[0] = o0;
  op[1] = o1;
}

extern "C" void kernel_launch(void* const* d_in, const int* in_sizes, int n_in,
                              void* d_out, int out_size, void* d_ws, size_t ws_size,
                              hipStream_t stream) {
  const float* x   = (const float*)d_in[0];
  const float* gw  = (const float*)d_in[1];
  const float* w13 = (const float*)d_in[2];
  const float* w2  = (const float*)d_in[3];
  float* out = (float*)d_out;
  float* logits = out + (size_t)T_TOK * HID;

  uint8_t* p = (uint8_t*)d_ws;
  unsigned short* xb   = (unsigned short*)p; p += (size_t)T_TOK * HID * 2;
  unsigned short* w13b = (unsigned short*)p; p += (size_t)NE * 2 * FFNW * HID * 2;
  unsigned short* w2b  = (unsigned short*)p; p += (size_t)NE * HID * FFNW * 2;
  unsigned short* act  = (unsigned short*)p; p += (size_t)NPAIR * FFNW * 2;
  unsigned short* y    = (unsigned short*)p; p += (size_t)NPAIR * HID * 2;
  int* sel  = (int*)p;   p += (size_t)NPAIR * 4;
  float* cw = (float*)p; p += (size_t)NPAIR * 4;
  int* tokc = (int*)p;   p += (size_t)NPAIR * 4;
  int* inv  = (int*)p;   p += (size_t)NPAIR * 4;
  u16* lrank = (u16*)p;  p += (size_t)NPAIR * 2;
  int* blkcnt = (int*)p; p += 32 * NE * 4;
  int* counts = (int*)p; p += 256;
  int* base   = (int*)p; p += 256;
  if ((size_t)(p - (uint8_t*)d_ws) > ws_size) return;

  // Order chosen for L3 residency: w13b+xb are written immediately before GEMM1
  // consumes them; w2b+act immediately before GEMM2.
  k_cast<<<2048, 256, 0, stream>>>(w13, w13b, (long)NE * 2 * FFNW * HID / 8);
  k_router<<<T_TOK / 4, 256, 0, stream>>>(x, gw, xb, logits, sel, cw);
  k_count<<<32, 256, 0, stream>>>(sel, lrank, blkcnt);
  k_scanplace<<<32, 256, 0, stream>>>(sel, lrank, blkcnt, tokc, inv, counts, base);

  // GEMM1 + fused SwiGLU: act[pair][F]  (128 rows x 64 act-cols per block, 2 blk/CU)
  k_gemm<true, HID, FFNW><<<4096, 256, 0, stream>>>(xb, w13b, act, counts, base, tokc);

  k_cast<<<2048, 256, 0, stream>>>(w2, w2b, (long)NE * HID * FFNW / 8);

  // GEMM2: y[pair][H]  (128 rows x 128 cols per block, 2 blk/CU)
  k_gemm<false, FFNW, HID><<<4096, 256, 0, stream>>>(act, w2b, y, counts, base, tokc);
  // combine into out
  k_combine<<<(int)((long)T_TOK * HID / 8 / 256), 256, 0, stream>>>(y, inv, cw, out);
}